// Round 1
// baseline (26397.641 us; speedup 1.0000x reference)
//
#include <hip/hip_runtime.h>
#include <math.h>

#define NN   1024
#define TTL  128
#define NTP  131072   // NN*TTL
#define TOPK 30

// ---- fp64 weight region offsets (in doubles) ----
#define OW_START 0
#define OB_START 16
#define OETF_W  32
#define OETF_B  800
#define OETG_W  816
#define OETG_B  1584
#define OEM0    1600
#define OEM1    1856
#define OEM2    2112
#define OEBB    2368
#define OEEND_W 2384
#define OEEND_B 2896
#define OEOUT_W 2928
#define OEOUT_B 4976
#define ODTF_W  5040
#define ODTF_B  17328
#define ODTG_W  17392
#define ODTG_B  29680
#define ODM0    29744
#define ODM1    33840
#define ODM2    37936
#define ODBB    42032
#define ODEND_W 42096
#define ODEND_B 44144
#define ODOUT_W 44176
#define ODOUT_B 44688
#define OWEND   44704
#define OBEND   44720
#define WTOT    45056

// ============ setup kernels ============

__global__ void k_prep_weights(
    const float* __restrict__ w_start, const float* __restrict__ b_start,
    const float* __restrict__ etf_w, const float* __restrict__ etf_b,
    const float* __restrict__ etg_w, const float* __restrict__ etg_b,
    const float* __restrict__ eg1_w, const float* __restrict__ eg1_b,
    const float* __restrict__ eg2_w, const float* __restrict__ eg2_b,
    const float* __restrict__ eend_w, const float* __restrict__ eend_b,
    const float* __restrict__ eout_w, const float* __restrict__ eout_b,
    const float* __restrict__ dtf_w, const float* __restrict__ dtf_b,
    const float* __restrict__ dtg_w, const float* __restrict__ dtg_b,
    const float* __restrict__ dg1_w, const float* __restrict__ dg1_b,
    const float* __restrict__ dg2_w, const float* __restrict__ dg2_b,
    const float* __restrict__ dend_w, const float* __restrict__ dend_b,
    const float* __restrict__ dout_w, const float* __restrict__ dout_b,
    const float* __restrict__ w_end, const float* __restrict__ b_end,
    double* __restrict__ W)
{
    int tid = blockIdx.x*blockDim.x + threadIdx.x;
    int nthr = gridDim.x*blockDim.x;
    for (int i=tid;i<16;i+=nthr){
        W[OW_START+i] = (double)w_start[i];
        W[OB_START+i] = (double)b_start[i];
        W[OETF_B+i]   = (double)etf_b[i];
        W[OETG_B+i]   = (double)etg_b[i];
        W[OEBB+i]     = (double)eg1_b[i] + (double)eg2_b[i];
        W[ODOUT_B+i]  = (double)dout_b[i];
        W[OWEND+i]    = (double)w_end[i];
    }
    for (int i=tid;i<768;i+=nthr){ W[OETF_W+i]=(double)etf_w[i]; W[OETG_W+i]=(double)etg_w[i]; }
    for (int i=tid;i<256;i+=nthr){
        int o=i>>4, c=i&15;
        W[OEM0+i] = (double)eg1_w[o*32+c] + (double)eg2_w[o*32+c]
                  + 0.05*((double)eg1_w[o*32+16+c] + (double)eg2_w[o*32+16+c]);
        W[OEM1+i] = 0.95*(double)eg1_w[o*32+16+c];
        W[OEM2+i] = 0.95*(double)eg2_w[o*32+16+c];
    }
    for (int i=tid;i<512;i+=nthr){ W[OEEND_W+i]=(double)eend_w[i]; W[ODOUT_W+i]=(double)dout_w[i]; }
    for (int i=tid;i<2048;i+=nthr){ W[OEOUT_W+i]=(double)eout_w[i]; W[ODEND_W+i]=(double)dend_w[i]; }
    for (int i=tid;i<12288;i+=nthr){ W[ODTF_W+i]=(double)dtf_w[i]; W[ODTG_W+i]=(double)dtg_w[i]; }
    for (int i=tid;i<4096;i+=nthr){
        int o=i>>6, c=i&63;
        W[ODM0+i] = (double)dg1_w[o*128+c] + (double)dg2_w[o*128+c]
                  + 0.05*((double)dg1_w[o*128+64+c] + (double)dg2_w[o*128+64+c]);
        W[ODM1+i] = 0.95*(double)dg1_w[o*128+64+c];
        W[ODM2+i] = 0.95*(double)dg2_w[o*128+64+c];
    }
    for (int i=tid;i<64;i+=nthr){
        W[ODTF_B+i]=(double)dtf_b[i]; W[ODTG_B+i]=(double)dtg_b[i];
        W[ODBB+i]=(double)dg1_b[i]+(double)dg2_b[i];
        W[OEOUT_B+i]=(double)eout_b[i];
    }
    for (int i=tid;i<32;i+=nthr){ W[OEEND_B+i]=(double)eend_b[i]; W[ODEND_B+i]=(double)dend_b[i]; }
    if (tid==0) W[OBEND] = (double)b_end[0];
}

__global__ void k_emb(const int* __restrict__ idxp,
                      const float* __restrict__ emb1, const float* __restrict__ emb2,
                      const float* __restrict__ l1w, const float* __restrict__ l1b,
                      const float* __restrict__ l2w, const float* __restrict__ l2b,
                      double* __restrict__ n1, double* __restrict__ n2)
{
    int id = blockIdx.x*blockDim.x + threadIdx.x;   // 65536
    int i = id>>6, d = id&63;
    int ii = idxp[i];
    double a1 = (double)l1b[d], a2 = (double)l2b[d];
    for (int k=0;k<64;k++){
        a1 += (double)emb1[ii*64+k]*(double)l1w[d*64+k];
        a2 += (double)emb2[ii*64+k]*(double)l2w[d*64+k];
    }
    n1[id] = tanh(3.0*a1);
    n2[id] = tanh(3.0*a2);
}

// one wave per row: scores + top-30 (ties -> lowest index, matching lax.top_k)
__global__ __launch_bounds__(64) void k_topk(
    const double* __restrict__ n1, const double* __restrict__ n2,
    int* __restrict__ topc, double* __restrict__ topv,
    double* __restrict__ rs1, double* __restrict__ colsum)
{
    __shared__ double arow[NN];
    __shared__ double sn1[64], sn2[64];
    int i = blockIdx.x, lane = threadIdx.x;
    sn1[lane] = n1[i*64+lane];
    sn2[lane] = n2[i*64+lane];
    __syncthreads();
    for (int jb=0;jb<16;jb++){
        int j = jb*64 + lane;
        const double* p2 = n2 + j*64;
        const double* p1 = n1 + j*64;
        double d1v=0.0, d2v=0.0;
        for (int d=0;d<64;d++){ d1v += sn1[d]*p2[d]; d2v += sn2[d]*p1[d]; }
        double a = tanh(3.0*(d1v - d2v));
        arow[j] = a>0.0 ? a : 0.0;
    }
    __syncthreads();
    double rsum = 0.0;
    for (int r=0;r<TOPK;r++){
        double bv = -2.0; int bj = 1<<30;
        for (int jb=0;jb<16;jb++){
            int j = jb*64+lane;
            double v = arow[j];
            if (v>bv || (v==bv && j<bj)){ bv=v; bj=j; }
        }
        for (int off=32; off>=1; off>>=1){
            double ov = __shfl_xor(bv, off, 64);
            int    oj = __shfl_xor(bj, off, 64);
            if (ov>bv || (ov==bv && oj<bj)){ bv=ov; bj=oj; }
        }
        if (lane == (bj & 63)) arow[bj] = -2.0;
        if (lane == 0){
            topc[i*TOPK+r] = bj;
            topv[i*TOPK+r] = bv;
            if (bv > 0.0) atomicAdd(&colsum[bj], bv);
        }
        rsum += (bv > 0.0 ? bv : 0.0);
        __syncthreads();
    }
    if (lane == 0) rs1[i] = 1.0 + rsum;
}

__global__ void k_csc(const int* __restrict__ topc, const double* __restrict__ topv,
                      const double* __restrict__ rs1,
                      int* __restrict__ ccount, int* __restrict__ cidx, double* __restrict__ cw)
{
    int w = blockIdx.x*blockDim.x + threadIdx.x;
    if (w >= NN) return;
    double rv = rs1[w];
    for (int r=0;r<TOPK;r++){
        double v = topv[w*TOPK+r];
        if (v > 0.0){
            int col = topc[w*TOPK+r];
            int pos = atomicAdd(&ccount[col], 1);
            cidx[(long)col*NN+pos] = w;
            cw  [(long)col*NN+pos] = v / rv;
        }
    }
}

__global__ void k_post1(const double* __restrict__ colsum, const double* __restrict__ rs1,
                        double* __restrict__ rs2, double* __restrict__ d1, double* __restrict__ d2)
{
    int v = blockIdx.x*blockDim.x + threadIdx.x;
    if (v >= NN) return;
    double r2 = 1.0 + colsum[v];
    rs2[v] = r2;
    d2[v] = 1.0/r2;
    d1[v] = 1.0/rs1[v];
}

__global__ void k_post2(const int* __restrict__ topc, const double* __restrict__ topv,
                        const double* __restrict__ rs2, double* __restrict__ ew2)
{
    int e = blockIdx.x*blockDim.x + threadIdx.x;
    if (e >= NN*TOPK) return;
    double v = topv[e];
    ew2[e] = (v > 0.0) ? v / rs2[topc[e]] : 0.0;
}

// ============ per-batch-chunk kernels ============

// x[B,T,N] fp32 -> h0[c][cb][n][t] fp64, c<16 (transpose via LDS tile)
__global__ __launch_bounds__(256) void k_start(const float* __restrict__ x, double* __restrict__ h0,
    const double* __restrict__ W, long S, int b0)
{
    __shared__ float tile[32][33];
    int cb = blockIdx.z;
    int t0 = blockIdx.x*32, n0 = blockIdx.y*32;
    const float* xb = x + (long)(b0+cb)*TTL*NN;
    int tx = threadIdx.x, ty = threadIdx.y;
    for (int r=0;r<4;r++){
        int tl = ty + 8*r;
        tile[tl][tx] = xb[(long)(t0+tl)*NN + n0 + tx];
    }
    __syncthreads();
    long basep = (long)cb*NTP + (long)n0*TTL + t0;
    for (int c=0;c<16;c++){
        double wc = W[OW_START+c], bc = W[OB_START+c];
        double* hp = h0 + (long)c*S + basep;
        for (int r=0;r<4;r++){
            int nl = ty + 8*r;
            hp[(long)nl*TTL + tx] = wc*(double)tile[tx][nl] + bc;
        }
    }
}

// gated temporal conv: y[o] = tanh(tconv_tf(x))[o] * sigmoid(tconv_tg(x))[o]
template<int CI>
__global__ __launch_bounds__(256) void k_gate(const double* __restrict__ x, double* __restrict__ y,
    const double* __restrict__ Wtf, const double* __restrict__ Btf,
    const double* __restrict__ Wtg, const double* __restrict__ Btg, long S)
{
    long p = (long)blockIdx.x*256 + threadIdx.x;
    int t = (int)(p & (TTL-1));
    int o0 = blockIdx.y*16;
    double atf[16], atg[16];
    #pragma unroll
    for (int o=0;o<16;o++){ atf[o]=Btf[o0+o]; atg[o]=Btg[o0+o]; }
    for (int i=0;i<CI;i++){
        const double* xp = x + (long)i*S + p;
        double xl = (t>0)      ? xp[-1] : 0.0;
        double xc = xp[0];
        double xr = (t<TTL-1)  ? xp[1]  : 0.0;
        const double* wf = Wtf + (long)o0*CI*3 + i*3;
        const double* wg = Wtg + (long)o0*CI*3 + i*3;
        #pragma unroll
        for (int o=0;o<16;o++){
            atf[o] += wf[(long)o*CI*3]*xl + wf[(long)o*CI*3+1]*xc + wf[(long)o*CI*3+2]*xr;
            atg[o] += wg[(long)o*CI*3]*xl + wg[(long)o*CI*3+1]*xc + wg[(long)o*CI*3+2]*xr;
        }
    }
    #pragma unroll
    for (int o=0;o<16;o++){
        double tf = tanh(atf[o]);
        double sg = 1.0/(1.0+exp(-atg[o]));
        y[(long)(o0+o)*S + p] = tf*sg;
    }
}

// sparse graph diffusion; one channel per block, node slice staged in LDS (64 KB)
// mode: 0 = both s1 (x@A1) and s2 (x@A2), 1 = s1 only, 2 = s2 only
__global__ __launch_bounds__(256) void k_graph(const double* __restrict__ g,
    double* __restrict__ s1, double* __restrict__ s2,
    const int* __restrict__ ccount, const int* __restrict__ cidx, const double* __restrict__ cw,
    const int* __restrict__ topc, const double* __restrict__ ew2,
    const double* __restrict__ d1, const double* __restrict__ d2,
    long S, int mode)
{
    __shared__ double ldsg[NN*8];
    int tid = threadIdx.x;
    long base = (long)blockIdx.y*S + (long)blockIdx.z*NTP;
    int t0 = blockIdx.x*8;
    const double* gp = g + base;
    for (int k=0;k<32;k++){
        int idx = k*256 + tid;
        int v = idx>>3, tl = idx&7;
        ldsg[idx] = gp[(long)v*TTL + t0 + tl];
    }
    __syncthreads();
    int wi = tid>>3, tl = tid&7;
    for (int wb=0;wb<32;wb++){
        int w = wb*32 + wi;
        double gc = ldsg[w*8+tl];
        long p = base + (long)w*TTL + t0 + tl;
        if (mode != 2){
            double a1 = gc*d1[w];
            int cnt = ccount[w];
            const int* ci = cidx + (long)w*NN;
            const double* cv = cw + (long)w*NN;
            for (int e=0;e<cnt;e++) a1 += cv[e]*ldsg[ci[e]*8+tl];
            s1[p] = a1;
        }
        if (mode != 1){
            double a2 = gc*d2[w];
            const int* tc = topc + w*TOPK;
            const double* e2 = ew2 + w*TOPK;
            for (int r=0;r<TOPK;r++){
                double wv = e2[r];
                if (wv != 0.0) a2 += wv*ldsg[tc[r]*8+tl];
            }
            s2[p] = a2;
        }
    }
}

// 1x1 conv: y[o0+o] (=|+=) sum_i Wm[o0+o][i]*x[i] (+bias), optional relu
template<int O, int I, bool RELU, bool DOACC>
__global__ __launch_bounds__(256) void k_conv1x1(const double* __restrict__ x, double* __restrict__ y,
    const double* __restrict__ Wm, const double* __restrict__ bias, long S)
{
    long p = (long)blockIdx.x*256 + threadIdx.x;
    int o0 = blockIdx.y*O;
    double acc[O];
    #pragma unroll
    for (int o=0;o<O;o++) acc[o] = DOACC ? y[(long)(o0+o)*S+p] : bias[o0+o];
    for (int i=0;i<I;i++){
        double xv = x[(long)i*S+p];
        const double* wr = Wm + (long)o0*I + i;
        #pragma unroll
        for (int o=0;o<O;o++) acc[o] += wr[(long)o*I]*xv;
    }
    #pragma unroll
    for (int o=0;o<O;o++){
        double v = acc[o];
        if (RELU) v = v>0.0 ? v : 0.0;
        y[(long)(o0+o)*S+p] = v;
    }
}

// final 16->1 conv + transpose back to [B,T,N] fp32
__global__ __launch_bounds__(256) void k_final(const double* __restrict__ o16, const double* __restrict__ W,
    float* __restrict__ out, long S, int b0)
{
    __shared__ float tile[32][33];
    int cb = blockIdx.z;
    int t0 = blockIdx.x*32, n0 = blockIdx.y*32;
    int tx = threadIdx.x, ty = threadIdx.y;
    long basep = (long)cb*NTP + (long)n0*TTL + t0;
    double wv[16];
    #pragma unroll
    for (int c=0;c<16;c++) wv[c] = W[OWEND+c];
    double bb = W[OBEND];
    for (int r=0;r<4;r++){
        int nl = ty + 8*r;
        long p = basep + (long)nl*TTL + tx;
        double a = bb;
        #pragma unroll
        for (int c=0;c<16;c++) a += wv[c]*o16[(long)c*S + p];
        tile[nl][tx] = (float)a;
    }
    __syncthreads();
    float* ob = out + (long)(b0+cb)*TTL*NN;
    for (int r=0;r<4;r++){
        int tl = ty + 8*r;
        ob[(long)(t0+tl)*NN + n0 + tx] = tile[tx][tl];
    }
}

// ============ launch ============

extern "C" void kernel_launch(void* const* d_in, const int* in_sizes, int n_in,
                              void* d_out, int out_size, void* d_ws, size_t ws_size,
                              hipStream_t stream)
{
    const float* x      = (const float*)d_in[0];
    const int*   idx    = (const int*)  d_in[1];
    const float* emb1   = (const float*)d_in[2];
    const float* emb2   = (const float*)d_in[3];
    const float* lin1_w = (const float*)d_in[4];
    const float* lin1_b = (const float*)d_in[5];
    const float* lin2_w = (const float*)d_in[6];
    const float* lin2_b = (const float*)d_in[7];
    const float* w_start= (const float*)d_in[8];
    const float* b_start= (const float*)d_in[9];
    const float* etf_w  = (const float*)d_in[10];
    const float* etf_b  = (const float*)d_in[11];
    const float* etg_w  = (const float*)d_in[12];
    const float* etg_b  = (const float*)d_in[13];
    const float* eg1_w  = (const float*)d_in[14];
    const float* eg1_b  = (const float*)d_in[15];
    const float* eg2_w  = (const float*)d_in[16];
    const float* eg2_b  = (const float*)d_in[17];
    const float* eend_w = (const float*)d_in[18];
    const float* eend_b = (const float*)d_in[19];
    const float* eout_w = (const float*)d_in[20];
    const float* eout_b = (const float*)d_in[21];
    const float* dtf_w  = (const float*)d_in[22];
    const float* dtf_b  = (const float*)d_in[23];
    const float* dtg_w  = (const float*)d_in[24];
    const float* dtg_b  = (const float*)d_in[25];
    const float* dg1_w  = (const float*)d_in[26];
    const float* dg1_b  = (const float*)d_in[27];
    const float* dg2_w  = (const float*)d_in[28];
    const float* dg2_b  = (const float*)d_in[29];
    const float* dend_w = (const float*)d_in[30];
    const float* dend_b = (const float*)d_in[31];
    const float* dout_w = (const float*)d_in[32];
    const float* dout_b = (const float*)d_in[33];
    const float* w_end  = (const float*)d_in[34];
    const float* b_end  = (const float*)d_in[35];
    float* out = (float*)d_out;

    char* base = (char*)d_ws;
    size_t cur = 0;
    auto alloc = [&](size_t bytes)->void* {
        void* p = base + cur;
        cur = (cur + bytes + 511) & ~(size_t)511;
        return p;
    };
    double* W     = (double*)alloc(WTOT*sizeof(double));
    double* n1    = (double*)alloc(65536*sizeof(double));
    double* n2    = (double*)alloc(65536*sizeof(double));
    double* topv  = (double*)alloc((size_t)NN*TOPK*sizeof(double));
    int*    topc  = (int*)   alloc((size_t)NN*TOPK*sizeof(int));
    double* rs1   = (double*)alloc(NN*sizeof(double));
    double* rs2   = (double*)alloc(NN*sizeof(double));
    double* colsum= (double*)alloc(NN*sizeof(double));
    double* d1a   = (double*)alloc(NN*sizeof(double));
    double* d2a   = (double*)alloc(NN*sizeof(double));
    double* ew2   = (double*)alloc((size_t)NN*TOPK*sizeof(double));
    int*    ccount= (int*)   alloc(NN*sizeof(int));
    int*    cidx  = (int*)   alloc((size_t)NN*NN*sizeof(int));
    double* cw    = (double*)alloc((size_t)NN*NN*sizeof(double));

    // pick largest batch-chunk that fits: arena = (3*64 + 32) ch-planes of CB*NTP doubles
    size_t perb = (size_t)224 * NTP * sizeof(double);
    int CB = 1;
    for (int c = 16; c >= 1; c >>= 1){
        if (cur + perb*(size_t)c <= ws_size){ CB = c; break; }
    }
    long S = (long)CB * NTP;
    double* R1 = (double*)alloc((size_t)64*S*sizeof(double));
    double* R2 = (double*)alloc((size_t)64*S*sizeof(double));
    double* R3 = (double*)alloc((size_t)64*S*sizeof(double));
    double* R4 = (double*)alloc((size_t)32*S*sizeof(double));

    (void)hipMemsetAsync(colsum, 0, NN*sizeof(double), stream);
    (void)hipMemsetAsync(ccount, 0, NN*sizeof(int), stream);

    k_prep_weights<<<32,256,0,stream>>>(
        w_start,b_start, etf_w,etf_b, etg_w,etg_b, eg1_w,eg1_b, eg2_w,eg2_b,
        eend_w,eend_b, eout_w,eout_b, dtf_w,dtf_b, dtg_w,dtg_b, dg1_w,dg1_b,
        dg2_w,dg2_b, dend_w,dend_b, dout_w,dout_b, w_end,b_end, W);
    k_emb<<<256,256,0,stream>>>(idx, emb1, emb2, lin1_w, lin1_b, lin2_w, lin2_b, n1, n2);
    k_topk<<<NN,64,0,stream>>>(n1, n2, topc, topv, rs1, colsum);
    k_csc<<<4,256,0,stream>>>(topc, topv, rs1, ccount, cidx, cw);
    k_post1<<<4,256,0,stream>>>(colsum, rs1, rs2, d1a, d2a);
    k_post2<<<(NN*TOPK+255)/256,256,0,stream>>>(topc, topv, rs2, ew2);

    int nch = 16 / CB;
    dim3 tb(32,8);
    int PB = 512*CB;   // blocks of 256 covering CB*NTP points
    for (int ch=0; ch<nch; ch++){
        int b0 = ch*CB;
        // ---- encoder (C=16) ----
        k_start<<<dim3(4,32,CB),tb,0,stream>>>(x, R1, W, S, b0);
        k_gate<16><<<dim3(PB,1),256,0,stream>>>(R1, R2, W+OETF_W, W+OETF_B, W+OETG_W, W+OETG_B, S);
        k_graph<<<dim3(16,16,CB),256,0,stream>>>(R2, R4, R4+(long)16*S,
            ccount,cidx,cw, topc,ew2, d1a,d2a, S, 0);
        k_conv1x1<16,16,false,false><<<dim3(PB,1),256,0,stream>>>(R2, R1, W+OEM0, W+OEBB, S);
        k_conv1x1<16,16,false,true ><<<dim3(PB,1),256,0,stream>>>(R4, R1, W+OEM1, W+OEBB, S);
        k_conv1x1<16,16,false,true ><<<dim3(PB,1),256,0,stream>>>(R4+(long)16*S, R1, W+OEM2, W+OEBB, S);
        k_conv1x1<32,16,true ,false><<<dim3(PB,1),256,0,stream>>>(R1, R4, W+OEEND_W, W+OEEND_B, S);
        k_conv1x1<32,32,false,false><<<dim3(PB,2),256,0,stream>>>(R4, R3, W+OEOUT_W, W+OEOUT_B, S);
        // ---- decoder (C=64) ----
        k_gate<64><<<dim3(PB,4),256,0,stream>>>(R3, R2, W+ODTF_W, W+ODTF_B, W+ODTG_W, W+ODTG_B, S);
        k_graph<<<dim3(16,64,CB),256,0,stream>>>(R2, R1, R1,
            ccount,cidx,cw, topc,ew2, d1a,d2a, S, 1);
        k_conv1x1<32,64,false,false><<<dim3(PB,2),256,0,stream>>>(R2, R3, W+ODM0, W+ODBB, S);
        k_conv1x1<32,64,false,true ><<<dim3(PB,2),256,0,stream>>>(R1, R3, W+ODM1, W+ODBB, S);
        k_graph<<<dim3(16,64,CB),256,0,stream>>>(R2, R1, R1,
            ccount,cidx,cw, topc,ew2, d1a,d2a, S, 2);
        k_conv1x1<32,64,false,true ><<<dim3(PB,2),256,0,stream>>>(R1, R3, W+ODM2, W+ODBB, S);
        k_conv1x1<32,64,true ,false><<<dim3(PB,1),256,0,stream>>>(R3, R4, W+ODEND_W, W+ODEND_B, S);
        k_conv1x1<16,32,false,false><<<dim3(PB,1),256,0,stream>>>(R4, R1, W+ODOUT_W, W+ODOUT_B, S);
        k_final<<<dim3(4,32,CB),tb,0,stream>>>(R1, W, out, S, b0);
    }
    (void)in_sizes; (void)n_in; (void)out_size; (void)ws_size;
}

// Round 2
// 25098.445 us; speedup vs baseline: 1.0518x; 1.0518x over previous
//
#include <hip/hip_runtime.h>
#include <math.h>

#define NN   1024
#define TTL  128
#define NTP  131072   // NN*TTL
#define TOPK 30

// ---- fp64 weight region offsets (in doubles) ----
#define OEGTF_T 0
#define OEGTF_C 48
#define OEGTF_B 96
#define OEGTG_T 112
#define OEGTG_C 160
#define OEGTG_B 208
#define OEM0    224
#define OEM1    480
#define OEM2    736
#define OEBB    992
#define OEEND_W 1008
#define OEEND_B 1520
#define OEOUT_W 1552
#define OEOUT_B 3600
#define ODTF_W  3664
#define ODTF_B  15952
#define ODTG_W  16016
#define ODTG_B  28304
#define ODM0    28368
#define ODM1    32464
#define ODM2    36560
#define ODBB    40656
#define ODEND_W 40720
#define ODEND_B 42768
#define ODOUT_W 42800
#define ODOUT_B 43312
#define OWEND   43328
#define OBEND   43344
#define WTOT    43520

// ============ setup kernels ============

__global__ void k_prep_weights(
    const float* __restrict__ w_start, const float* __restrict__ b_start,
    const float* __restrict__ etf_w, const float* __restrict__ etf_b,
    const float* __restrict__ etg_w, const float* __restrict__ etg_b,
    const float* __restrict__ eg1_w, const float* __restrict__ eg1_b,
    const float* __restrict__ eg2_w, const float* __restrict__ eg2_b,
    const float* __restrict__ eend_w, const float* __restrict__ eend_b,
    const float* __restrict__ eout_w, const float* __restrict__ eout_b,
    const float* __restrict__ dtf_w, const float* __restrict__ dtf_b,
    const float* __restrict__ dtg_w, const float* __restrict__ dtg_b,
    const float* __restrict__ dg1_w, const float* __restrict__ dg1_b,
    const float* __restrict__ dg2_w, const float* __restrict__ dg2_b,
    const float* __restrict__ dend_w, const float* __restrict__ dend_b,
    const float* __restrict__ dout_w, const float* __restrict__ dout_b,
    const float* __restrict__ w_end, const float* __restrict__ b_end,
    double* __restrict__ W)
{
    int tid = blockIdx.x*blockDim.x + threadIdx.x;
    int nthr = gridDim.x*blockDim.x;
    // encoder gate collapsed through w_start: tap[o][k] = sum_i w[o,i,k]*ws[i]
    for (int id=tid; id<96; id+=nthr){
        int which = id/48; int r = id%48; int o = r/3, k = r%3;
        const float* w = which ? etg_w : etf_w;
        double t=0.0, c=0.0;
        for (int i=0;i<16;i++){
            double wv = (double)w[(o*16+i)*3+k];
            t += wv*(double)w_start[i];
            c += wv*(double)b_start[i];
        }
        W[(which?OEGTG_T:OEGTF_T)+o*3+k] = t;
        W[(which?OEGTG_C:OEGTF_C)+o*3+k] = c;
    }
    for (int i=tid;i<16;i+=nthr){
        W[OEGTF_B+i] = (double)etf_b[i];
        W[OEGTG_B+i] = (double)etg_b[i];
        W[OEBB+i]    = (double)eg1_b[i] + (double)eg2_b[i];
        W[ODOUT_B+i] = (double)dout_b[i];
        W[OWEND+i]   = (double)w_end[i];
    }
    // enc mix transposed [i][o]
    for (int id=tid;id<256;id+=nthr){
        int o=id&15, i=id>>4;
        W[OEM0+i*16+o] = (double)eg1_w[o*32+i] + (double)eg2_w[o*32+i]
                       + 0.05*((double)eg1_w[o*32+16+i] + (double)eg2_w[o*32+16+i]);
        W[OEM1+i*16+o] = 0.95*(double)eg1_w[o*32+16+i];
        W[OEM2+i*16+o] = 0.95*(double)eg2_w[o*32+16+i];
    }
    for (int id=tid;id<512;id+=nthr){
        W[OEEND_W+id] = (double)eend_w[id];   // [32][16]
        W[ODOUT_W+id] = (double)dout_w[id];   // [16][32]
    }
    for (int id=tid;id<2048;id+=nthr){
        W[OEOUT_W+id] = (double)eout_w[id];   // [64][32]
        W[ODEND_W+id] = (double)dend_w[id];   // [32][64]
    }
    // dec tconv weights relaid as [i][o][k]
    for (int id=tid;id<12288;id+=nthr){
        int i = id/192; int rem = id%192; int o = rem/3, k = rem%3;
        W[ODTF_W+id] = (double)dtf_w[(o*64+i)*3+k];
        W[ODTG_W+id] = (double)dtg_w[(o*64+i)*3+k];
    }
    // dec mix transposed [i][o]
    for (int id=tid;id<4096;id+=nthr){
        int o=id&63, i=id>>6;
        W[ODM0+i*64+o] = (double)dg1_w[o*128+i] + (double)dg2_w[o*128+i]
                       + 0.05*((double)dg1_w[o*128+64+i] + (double)dg2_w[o*128+64+i]);
        W[ODM1+i*64+o] = 0.95*(double)dg1_w[o*128+64+i];
        W[ODM2+i*64+o] = 0.95*(double)dg2_w[o*128+64+i];
    }
    for (int i=tid;i<64;i+=nthr){
        W[ODTF_B+i]=(double)dtf_b[i]; W[ODTG_B+i]=(double)dtg_b[i];
        W[ODBB+i]=(double)dg1_b[i]+(double)dg2_b[i];
        W[OEOUT_B+i]=(double)eout_b[i];
    }
    for (int i=tid;i<32;i+=nthr){ W[OEEND_B+i]=(double)eend_b[i]; W[ODEND_B+i]=(double)dend_b[i]; }
    if (tid==0) W[OBEND] = (double)b_end[0];
}

__global__ void k_emb(const int* __restrict__ idxp,
                      const float* __restrict__ emb1, const float* __restrict__ emb2,
                      const float* __restrict__ l1w, const float* __restrict__ l1b,
                      const float* __restrict__ l2w, const float* __restrict__ l2b,
                      double* __restrict__ n1, double* __restrict__ n2)
{
    int id = blockIdx.x*blockDim.x + threadIdx.x;   // 65536
    int i = id>>6, d = id&63;
    int ii = idxp[i];
    double a1 = (double)l1b[d], a2 = (double)l2b[d];
    for (int k=0;k<64;k++){
        a1 += (double)emb1[ii*64+k]*(double)l1w[d*64+k];
        a2 += (double)emb2[ii*64+k]*(double)l2w[d*64+k];
    }
    n1[id] = tanh(3.0*a1);
    n2[id] = tanh(3.0*a2);
}

__global__ __launch_bounds__(64) void k_topk(
    const double* __restrict__ n1, const double* __restrict__ n2,
    int* __restrict__ topc, double* __restrict__ topv,
    double* __restrict__ rs1, double* __restrict__ colsum)
{
    __shared__ double arow[NN];
    __shared__ double sn1[64], sn2[64];
    int i = blockIdx.x, lane = threadIdx.x;
    sn1[lane] = n1[i*64+lane];
    sn2[lane] = n2[i*64+lane];
    __syncthreads();
    for (int jb=0;jb<16;jb++){
        int j = jb*64 + lane;
        const double* p2 = n2 + j*64;
        const double* p1 = n1 + j*64;
        double d1v=0.0, d2v=0.0;
        for (int d=0;d<64;d++){ d1v += sn1[d]*p2[d]; d2v += sn2[d]*p1[d]; }
        double a = tanh(3.0*(d1v - d2v));
        arow[j] = a>0.0 ? a : 0.0;
    }
    __syncthreads();
    double rsum = 0.0;
    for (int r=0;r<TOPK;r++){
        double bv = -2.0; int bj = 1<<30;
        for (int jb=0;jb<16;jb++){
            int j = jb*64+lane;
            double v = arow[j];
            if (v>bv || (v==bv && j<bj)){ bv=v; bj=j; }
        }
        for (int off=32; off>=1; off>>=1){
            double ov = __shfl_xor(bv, off, 64);
            int    oj = __shfl_xor(bj, off, 64);
            if (ov>bv || (ov==bv && oj<bj)){ bv=ov; bj=oj; }
        }
        if (lane == (bj & 63)) arow[bj] = -2.0;
        if (lane == 0){
            topc[i*TOPK+r] = bj;
            topv[i*TOPK+r] = bv;
            if (bv > 0.0) atomicAdd(&colsum[bj], bv);
        }
        rsum += (bv > 0.0 ? bv : 0.0);
        __syncthreads();
    }
    if (lane == 0) rs1[i] = 1.0 + rsum;
}

__global__ void k_csc(const int* __restrict__ topc, const double* __restrict__ topv,
                      const double* __restrict__ rs1,
                      int* __restrict__ ccount, int* __restrict__ cidx, double* __restrict__ cw)
{
    int w = blockIdx.x*blockDim.x + threadIdx.x;
    if (w >= NN) return;
    double rv = rs1[w];
    for (int r=0;r<TOPK;r++){
        double v = topv[w*TOPK+r];
        if (v > 0.0){
            int col = topc[w*TOPK+r];
            int pos = atomicAdd(&ccount[col], 1);
            cidx[(long)col*NN+pos] = w;
            cw  [(long)col*NN+pos] = v / rv;
        }
    }
}

__global__ void k_post1(const double* __restrict__ colsum, const double* __restrict__ rs1,
                        double* __restrict__ rs2, double* __restrict__ d1, double* __restrict__ d2)
{
    int v = blockIdx.x*blockDim.x + threadIdx.x;
    if (v >= NN) return;
    double r2 = 1.0 + colsum[v];
    rs2[v] = r2;
    d2[v] = 1.0/r2;
    d1[v] = 1.0/rs1[v];
}

__global__ void k_post2(const int* __restrict__ topc, const double* __restrict__ topv,
                        const double* __restrict__ rs2, double* __restrict__ ew2)
{
    int e = blockIdx.x*blockDim.x + threadIdx.x;
    if (e >= NN*TOPK) return;
    double v = topv[e];
    ew2[e] = (v > 0.0) ? v / rs2[topc[e]] : 0.0;
}

// x[B,T,N] fp32 -> xT[B,N,T] fp32
__global__ __launch_bounds__(256) void k_xT(const float* __restrict__ x, float* __restrict__ xT)
{
    __shared__ float tile[32][33];
    int b = blockIdx.z, t0 = blockIdx.x*32, n0 = blockIdx.y*32;
    int tx = threadIdx.x, ty = threadIdx.y;
    const float* xb = x + (long)b*NTP;
    for (int r=0;r<4;r++){
        int tl = ty + 8*r;
        tile[tl][tx] = xb[(long)(t0+tl)*NN + n0 + tx];
    }
    __syncthreads();
    float* ob = xT + (long)b*NTP;
    for (int r=0;r<4;r++){
        int nl = ty + 8*r;
        ob[(long)(n0+nl)*TTL + t0 + tx] = tile[tx][nl];
    }
}

// ============ fused pipeline kernels ============

// encoder: gate (collapsed taps) fused into graph staging; writes eg, es1, es2
__global__ __launch_bounds__(256) void k_enc_gg(const float* __restrict__ xT,
    double* __restrict__ eg, double* __restrict__ es1, double* __restrict__ es2,
    const double* __restrict__ Wt,
    const int* __restrict__ ccount, const int* __restrict__ cidx, const double* __restrict__ cw,
    const int* __restrict__ topc, const double* __restrict__ ew2,
    const double* __restrict__ d1, const double* __restrict__ d2,
    long S, int b0)
{
    __shared__ double ldsg[NN*8];
    int tid = threadIdx.x, c = blockIdx.y, cb = blockIdx.z, t0 = blockIdx.x*8;
    double ft[3], fc[3], gt[3], gcc[3];
    #pragma unroll
    for (int k=0;k<3;k++){
        ft[k]=Wt[OEGTF_T+c*3+k]; fc[k]=Wt[OEGTF_C+c*3+k];
        gt[k]=Wt[OEGTG_T+c*3+k]; gcc[k]=Wt[OEGTG_C+c*3+k];
    }
    double fb = Wt[OEGTF_B+c], gb = Wt[OEGTG_B+c];
    const float* xb = xT + (long)(b0+cb)*NTP;
    long base = (long)c*S + (long)cb*NTP;
    for (int k=0;k<32;k++){
        int idx = k*256 + tid;
        int v = idx>>3, tl = idx&7, t = t0+tl;
        const float* xp = xb + (long)v*TTL + t;
        double xc = (double)xp[0];
        double atf = fb + ft[1]*xc + fc[1];
        double atg = gb + gt[1]*xc + gcc[1];
        if (t>0){ double xl = (double)xp[-1]; atf += ft[0]*xl + fc[0]; atg += gt[0]*xl + gcc[0]; }
        if (t<TTL-1){ double xr = (double)xp[1]; atf += ft[2]*xr + fc[2]; atg += gt[2]*xr + gcc[2]; }
        double gv = tanh(atf)/(1.0+exp(-atg));
        ldsg[idx] = gv;
        eg[base + (long)v*TTL + t] = gv;
    }
    __syncthreads();
    int wi = tid>>3, tl = tid&7;
    for (int wb=0;wb<32;wb++){
        int w = wb*32 + wi;
        double gcv = ldsg[w*8+tl];
        long p = base + (long)w*TTL + t0 + tl;
        double a1 = gcv*d1[w];
        int cnt = ccount[w];
        const int* ci = cidx + (long)w*NN;
        const double* cv = cw + (long)w*NN;
        for (int e=0;e<cnt;e++) a1 += cv[e]*ldsg[ci[e]*8+tl];
        es1[p] = a1;
        double a2 = gcv*d2[w];
        const int* tc = topc + w*TOPK;
        const double* e2 = ew2 + w*TOPK;
        for (int r=0;r<TOPK;r++){
            double wv = e2[r];
            if (wv != 0.0) a2 += wv*ldsg[tc[r]*8+tl];
        }
        es2[p] = a2;
    }
}

// encoder tail: mix(M0,M1,M2)+bias -> relu(end) -> out, all in registers
__global__ __launch_bounds__(256) void k_enc_tail(const double* __restrict__ eg,
    const double* __restrict__ es1, const double* __restrict__ es2,
    double* __restrict__ A, const double* __restrict__ Wt, long S)
{
    long p = (long)blockIdx.x*256 + threadIdx.x;
    double m[16];
    #pragma unroll
    for (int o=0;o<16;o++) m[o] = Wt[OEBB+o];
    for (int i=0;i<16;i++){
        double a = eg[(long)i*S+p], b = es1[(long)i*S+p], c = es2[(long)i*S+p];
        const double* w0 = Wt+OEM0+i*16;
        const double* w1 = Wt+OEM1+i*16;
        const double* w2 = Wt+OEM2+i*16;
        #pragma unroll
        for (int o=0;o<16;o++) m[o] += w0[o]*a + w1[o]*b + w2[o]*c;
    }
    double e[32];
    #pragma unroll
    for (int o2=0;o2<32;o2++){
        double acc = Wt[OEEND_B+o2];
        #pragma unroll
        for (int i=0;i<16;i++) acc += Wt[OEEND_W+o2*16+i]*m[i];
        e[o2] = acc>0.0 ? acc : 0.0;
    }
    for (int o=0;o<64;o++){
        double acc = Wt[OEOUT_B+o];
        #pragma unroll
        for (int i=0;i<32;i++) acc += Wt[OEOUT_W+o*32+i]*e[i];
        A[(long)o*S+p] = acc;
    }
}

// decoder gated tconv: 2 points/thread, 16-out chunk (oc folded into bx, fastest for L2 reuse)
__global__ __launch_bounds__(256) void k_dec_gate(const double* __restrict__ A,
    double* __restrict__ g, const double* __restrict__ Wt, long S)
{
    int bx = blockIdx.x;
    int oc = bx & 3;
    long p0 = (long)(bx>>2)*512 + threadIdx.x;   // second point = p0+256 (same t)
    int t = (int)(p0 & (TTL-1));
    double af0[16], af1[16], ag0[16], ag1[16];
    #pragma unroll
    for (int o=0;o<16;o++){
        double bf = Wt[ODTF_B + oc*16 + o], bg = Wt[ODTG_B + oc*16 + o];
        af0[o]=bf; af1[o]=bf; ag0[o]=bg; ag1[o]=bg;
    }
    const double* Ap = A + p0;
    for (int i=0;i<64;i++){
        const double* xp = Ap + (long)i*S;
        double xc0 = xp[0], xc1 = xp[256];
        double xl0=0.0, xl1=0.0, xr0=0.0, xr1=0.0;
        if (t>0){ xl0 = xp[-1]; xl1 = xp[255]; }
        if (t<TTL-1){ xr0 = xp[1]; xr1 = xp[257]; }
        const double* wf = Wt + ODTF_W + (long)i*192 + oc*48;
        const double* wg = Wt + ODTG_W + (long)i*192 + oc*48;
        #pragma unroll
        for (int o=0;o<16;o++){
            double a = wf[o*3], b = wf[o*3+1], c = wf[o*3+2];
            af0[o] += a*xl0 + b*xc0 + c*xr0;
            af1[o] += a*xl1 + b*xc1 + c*xr1;
            double d = wg[o*3], e = wg[o*3+1], f = wg[o*3+2];
            ag0[o] += d*xl0 + e*xc0 + f*xr0;
            ag1[o] += d*xl1 + e*xc1 + f*xr1;
        }
    }
    #pragma unroll
    for (int o=0;o<16;o++){
        long q = (long)(oc*16+o)*S + p0;
        g[q]       = tanh(af0[o])/(1.0+exp(-ag0[o]));
        g[q + 256] = tanh(af1[o])/(1.0+exp(-ag1[o]));
    }
}

// decoder graph diffusion, both directions in one pass
__global__ __launch_bounds__(256) void k_dec_graph(const double* __restrict__ g,
    double* __restrict__ s1, double* __restrict__ s2,
    const int* __restrict__ ccount, const int* __restrict__ cidx, const double* __restrict__ cw,
    const int* __restrict__ topc, const double* __restrict__ ew2,
    const double* __restrict__ d1, const double* __restrict__ d2, long S)
{
    __shared__ double ldsg[NN*8];
    int tid = threadIdx.x;
    long base = (long)blockIdx.y*S + (long)blockIdx.z*NTP;
    int t0 = blockIdx.x*8;
    const double* gp = g + base;
    for (int k=0;k<32;k++){
        int idx = k*256 + tid;
        int v = idx>>3, tl = idx&7;
        ldsg[idx] = gp[(long)v*TTL + t0 + tl];
    }
    __syncthreads();
    int wi = tid>>3, tl = tid&7;
    for (int wb=0;wb<32;wb++){
        int w = wb*32 + wi;
        double gcv = ldsg[w*8+tl];
        long p = base + (long)w*TTL + t0 + tl;
        double a1 = gcv*d1[w];
        int cnt = ccount[w];
        const int* ci = cidx + (long)w*NN;
        const double* cv = cw + (long)w*NN;
        for (int e=0;e<cnt;e++) a1 += cv[e]*ldsg[ci[e]*8+tl];
        s1[p] = a1;
        double a2 = gcv*d2[w];
        const int* tc = topc + w*TOPK;
        const double* e2 = ew2 + w*TOPK;
        for (int r=0;r<TOPK;r++){
            double wv = e2[r];
            if (wv != 0.0) a2 += wv*ldsg[tc[r]*8+tl];
        }
        s2[p] = a2;
    }
}

// decoder tail: mix -> relu(end) -> out -> w_end dot -> fp32 [B,T,N]
__global__ __launch_bounds__(256) void k_dec_tail(const double* __restrict__ g,
    const double* __restrict__ s1, const double* __restrict__ s2,
    const double* __restrict__ Wt, float* __restrict__ out, long S, int b0)
{
    long p = (long)blockIdx.x*256 + threadIdx.x;
    double m[64];
    #pragma unroll
    for (int o=0;o<64;o++) m[o] = Wt[ODBB+o];
    for (int i=0;i<64;i++){
        double a = g[(long)i*S+p], b = s1[(long)i*S+p], c = s2[(long)i*S+p];
        const double* w0 = Wt+ODM0+i*64;
        const double* w1 = Wt+ODM1+i*64;
        const double* w2 = Wt+ODM2+i*64;
        #pragma unroll
        for (int o=0;o<64;o++) m[o] += w0[o]*a + w1[o]*b + w2[o]*c;
    }
    double e[32];
    #pragma unroll
    for (int o2=0;o2<32;o2++){
        double acc = Wt[ODEND_B+o2];
        #pragma unroll
        for (int i=0;i<64;i++) acc += Wt[ODEND_W+o2*64+i]*m[i];
        e[o2] = acc>0.0 ? acc : 0.0;
    }
    double o16[16];
    #pragma unroll
    for (int o3=0;o3<16;o3++){
        double acc = Wt[ODOUT_B+o3];
        #pragma unroll
        for (int i=0;i<32;i++) acc += Wt[ODOUT_W+o3*32+i]*e[i];
        o16[o3] = acc;
    }
    double res = Wt[OBEND];
    #pragma unroll
    for (int c=0;c<16;c++) res += Wt[OWEND+c]*o16[c];
    int cb = (int)(p >> 17);
    long r = p & (NTP-1);
    int v = (int)(r >> 7), t = (int)(r & (TTL-1));
    out[((long)(b0+cb)*TTL + t)*NN + v] = (float)res;
}

// ============ launch ============

extern "C" void kernel_launch(void* const* d_in, const int* in_sizes, int n_in,
                              void* d_out, int out_size, void* d_ws, size_t ws_size,
                              hipStream_t stream)
{
    const float* x      = (const float*)d_in[0];
    const int*   idx    = (const int*)  d_in[1];
    const float* emb1   = (const float*)d_in[2];
    const float* emb2   = (const float*)d_in[3];
    const float* lin1_w = (const float*)d_in[4];
    const float* lin1_b = (const float*)d_in[5];
    const float* lin2_w = (const float*)d_in[6];
    const float* lin2_b = (const float*)d_in[7];
    const float* w_start= (const float*)d_in[8];
    const float* b_start= (const float*)d_in[9];
    const float* etf_w  = (const float*)d_in[10];
    const float* etf_b  = (const float*)d_in[11];
    const float* etg_w  = (const float*)d_in[12];
    const float* etg_b  = (const float*)d_in[13];
    const float* eg1_w  = (const float*)d_in[14];
    const float* eg1_b  = (const float*)d_in[15];
    const float* eg2_w  = (const float*)d_in[16];
    const float* eg2_b  = (const float*)d_in[17];
    const float* eend_w = (const float*)d_in[18];
    const float* eend_b = (const float*)d_in[19];
    const float* eout_w = (const float*)d_in[20];
    const float* eout_b = (const float*)d_in[21];
    const float* dtf_w  = (const float*)d_in[22];
    const float* dtf_b  = (const float*)d_in[23];
    const float* dtg_w  = (const float*)d_in[24];
    const float* dtg_b  = (const float*)d_in[25];
    const float* dg1_w  = (const float*)d_in[26];
    const float* dg1_b  = (const float*)d_in[27];
    const float* dg2_w  = (const float*)d_in[28];
    const float* dg2_b  = (const float*)d_in[29];
    const float* dend_w = (const float*)d_in[30];
    const float* dend_b = (const float*)d_in[31];
    const float* dout_w = (const float*)d_in[32];
    const float* dout_b = (const float*)d_in[33];
    const float* w_end  = (const float*)d_in[34];
    const float* b_end  = (const float*)d_in[35];
    float* out = (float*)d_out;

    char* basep = (char*)d_ws;
    size_t cur = 0;
    auto alloc = [&](size_t bytes)->void* {
        void* p = basep + cur;
        cur = (cur + bytes + 511) & ~(size_t)511;
        return p;
    };
    double* W     = (double*)alloc(WTOT*sizeof(double));
    double* n1    = (double*)alloc(65536*sizeof(double));
    double* n2    = (double*)alloc(65536*sizeof(double));
    double* topv  = (double*)alloc((size_t)NN*TOPK*sizeof(double));
    int*    topc  = (int*)   alloc((size_t)NN*TOPK*sizeof(int));
    double* rs1   = (double*)alloc(NN*sizeof(double));
    double* rs2   = (double*)alloc(NN*sizeof(double));
    double* colsum= (double*)alloc(NN*sizeof(double));
    double* d1a   = (double*)alloc(NN*sizeof(double));
    double* d2a   = (double*)alloc(NN*sizeof(double));
    double* ew2   = (double*)alloc((size_t)NN*TOPK*sizeof(double));
    int*    ccount= (int*)   alloc(NN*sizeof(int));
    int*    cidx  = (int*)   alloc((size_t)NN*NN*sizeof(int));
    double* cw    = (double*)alloc((size_t)NN*NN*sizeof(double));
    float*  xT    = (float*) alloc((size_t)16*NTP*sizeof(float));

    // plane arena: A(64) + B(64) + C(64) channel planes of CB*NTP doubles
    size_t perb = (size_t)192 * NTP * sizeof(double);
    int CB = 1;
    for (int c = 16; c >= 1; c >>= 1){
        if (cur + perb*(size_t)c <= ws_size){ CB = c; break; }
    }
    long S = (long)CB * NTP;
    double* A = (double*)alloc((size_t)64*S*sizeof(double));
    double* B = (double*)alloc((size_t)64*S*sizeof(double));
    double* C = (double*)alloc((size_t)64*S*sizeof(double));

    (void)hipMemsetAsync(colsum, 0, NN*sizeof(double), stream);
    (void)hipMemsetAsync(ccount, 0, NN*sizeof(int), stream);

    k_prep_weights<<<32,256,0,stream>>>(
        w_start,b_start, etf_w,etf_b, etg_w,etg_b, eg1_w,eg1_b, eg2_w,eg2_b,
        eend_w,eend_b, eout_w,eout_b, dtf_w,dtf_b, dtg_w,dtg_b, dg1_w,dg1_b,
        dg2_w,dg2_b, dend_w,dend_b, dout_w,dout_b, w_end,b_end, W);
    k_emb<<<256,256,0,stream>>>(idx, emb1, emb2, lin1_w, lin1_b, lin2_w, lin2_b, n1, n2);
    k_topk<<<NN,64,0,stream>>>(n1, n2, topc, topv, rs1, colsum);
    k_csc<<<4,256,0,stream>>>(topc, topv, rs1, ccount, cidx, cw);
    k_post1<<<4,256,0,stream>>>(colsum, rs1, rs2, d1a, d2a);
    k_post2<<<(NN*TOPK+255)/256,256,0,stream>>>(topc, topv, rs2, ew2);
    k_xT<<<dim3(4,32,16),dim3(32,8),0,stream>>>(x, xT);

    int nch = 16 / CB;
    for (int ch=0; ch<nch; ch++){
        int b0 = ch*CB;
        // encoder: fused gate+graph -> eg(B[0:16]), es1(B[16:32]), es2(B[32:48])
        k_enc_gg<<<dim3(16,16,CB),256,0,stream>>>(xT, B, B+(long)16*S, B+(long)32*S, W,
            ccount,cidx,cw, topc,ew2, d1a,d2a, S, b0);
        // encoder tail -> A (64 planes)
        k_enc_tail<<<512*CB,256,0,stream>>>(B, B+(long)16*S, B+(long)32*S, A, W, S);
        // decoder gate: A -> B (g, 64 planes)
        k_dec_gate<<<1024*CB,256,0,stream>>>(A, B, W, S);
        // decoder graph: B -> C (s1), A (s2; overwrites dead R3)
        k_dec_graph<<<dim3(16,64,CB),256,0,stream>>>(B, C, A,
            ccount,cidx,cw, topc,ew2, d1a,d2a, S);
        // decoder tail -> out
        k_dec_tail<<<512*CB,256,0,stream>>>(B, C, A, W, out, S, b0);
    }
    (void)in_sizes; (void)n_in; (void)out_size;
}

// Round 3
// 21219.006 us; speedup vs baseline: 1.2441x; 1.1828x over previous
//
#include <hip/hip_runtime.h>
#include <math.h>

#define NN   1024
#define TTL  128
#define NTP  131072   // NN*TTL
#define TOPK 30

// ---- fp64 weight region offsets (in doubles) ----
#define OEGTF_T 0
#define OEGTF_C 48
#define OEGTF_B 96
#define OEGTG_T 112
#define OEGTG_C 160
#define OEGTG_B 208
#define OEE0    224
#define OEE1    736
#define OEE2    1248
#define OEEB    1760
#define OEOUT_W 1792
#define OEOUT_B 3840
#define ODTF_W  3904
#define ODTF_B  16192
#define ODTG_W  16256
#define ODTG_B  28544
#define ODE0    28608
#define ODE1    30656
#define ODE2    32704
#define ODEB    34752
#define OWC     34784
#define OBC     34816
#define WTOT    34880

// ============ setup kernels ============

__global__ void k_prep_weights(
    const float* __restrict__ w_start, const float* __restrict__ b_start,
    const float* __restrict__ etf_w, const float* __restrict__ etf_b,
    const float* __restrict__ etg_w, const float* __restrict__ etg_b,
    const float* __restrict__ eg1_w, const float* __restrict__ eg1_b,
    const float* __restrict__ eg2_w, const float* __restrict__ eg2_b,
    const float* __restrict__ eend_w, const float* __restrict__ eend_b,
    const float* __restrict__ eout_w, const float* __restrict__ eout_b,
    const float* __restrict__ dtf_w, const float* __restrict__ dtf_b,
    const float* __restrict__ dtg_w, const float* __restrict__ dtg_b,
    const float* __restrict__ dg1_w, const float* __restrict__ dg1_b,
    const float* __restrict__ dg2_w, const float* __restrict__ dg2_b,
    const float* __restrict__ dend_w, const float* __restrict__ dend_b,
    const float* __restrict__ dout_w, const float* __restrict__ dout_b,
    const float* __restrict__ w_end, const float* __restrict__ b_end,
    double* __restrict__ W)
{
    int tid = blockIdx.x*blockDim.x + threadIdx.x;
    int nthr = gridDim.x*blockDim.x;
    // encoder gate collapsed through w_start: tap[o][k] = sum_i w[o,i,k]*ws[i]
    for (int id=tid; id<96; id+=nthr){
        int which = id/48; int r = id%48; int o = r/3, k = r%3;
        const float* w = which ? etg_w : etf_w;
        double t=0.0, c=0.0;
        for (int i=0;i<16;i++){
            double wv = (double)w[(o*16+i)*3+k];
            t += wv*(double)w_start[i];
            c += wv*(double)b_start[i];
        }
        W[(which?OEGTG_T:OEGTF_T)+o*3+k] = t;
        W[(which?OEGTG_C:OEGTF_C)+o*3+k] = c;
    }
    for (int i=tid;i<16;i+=nthr){
        W[OEGTF_B+i] = (double)etf_b[i];
        W[OEGTG_B+i] = (double)etg_b[i];
    }
    // encoder fused (mix . end) matrices: Ee_k[i][o2] = sum_o eend_w[o2][o]*Mk[i][o]
    for (int id=tid; id<512; id+=nthr){
        int i = id>>5, o2 = id&31;
        double s0=0.0, s1=0.0, s2=0.0;
        for (int o=0;o<16;o++){
            double m0 = (double)eg1_w[o*32+i] + (double)eg2_w[o*32+i]
                      + 0.05*((double)eg1_w[o*32+16+i] + (double)eg2_w[o*32+16+i]);
            double m1 = 0.95*(double)eg1_w[o*32+16+i];
            double m2 = 0.95*(double)eg2_w[o*32+16+i];
            double ew = (double)eend_w[o2*16+o];
            s0 += ew*m0; s1 += ew*m1; s2 += ew*m2;
        }
        W[OEE0+i*32+o2]=s0; W[OEE1+i*32+o2]=s1; W[OEE2+i*32+o2]=s2;
    }
    for (int o2=tid; o2<32; o2+=nthr){
        double s = (double)eend_b[o2];
        for (int o=0;o<16;o++) s += (double)eend_w[o2*16+o]*((double)eg1_b[o]+(double)eg2_b[o]);
        W[OEEB+o2] = s;
    }
    for (int id=tid;id<2048;id+=nthr) W[OEOUT_W+id] = (double)eout_w[id];   // [64][32]
    for (int i=tid;i<64;i+=nthr)      W[OEOUT_B+i]  = (double)eout_b[i];
    // dec tconv weights relaid as [i][o][k]
    for (int id=tid;id<12288;id+=nthr){
        int i = id/192; int rem = id%192; int o = rem/3, k = rem%3;
        W[ODTF_W+id] = (double)dtf_w[(o*64+i)*3+k];
        W[ODTG_W+id] = (double)dtg_w[(o*64+i)*3+k];
    }
    for (int i=tid;i<64;i+=nthr){
        W[ODTF_B+i]=(double)dtf_b[i]; W[ODTG_B+i]=(double)dtg_b[i];
    }
    // decoder fused (mix . end) matrices: E_k[i][o2] = sum_o dend_w[o2][o]*Mk[i][o]
    for (int id=tid; id<2048; id+=nthr){
        int i = id>>5, o2 = id&31;
        double s0=0.0, s1=0.0, s2=0.0;
        for (int o=0;o<64;o++){
            double m0 = (double)dg1_w[o*128+i] + (double)dg2_w[o*128+i]
                      + 0.05*((double)dg1_w[o*128+64+i] + (double)dg2_w[o*128+64+i]);
            double m1 = 0.95*(double)dg1_w[o*128+64+i];
            double m2 = 0.95*(double)dg2_w[o*128+64+i];
            double ew = (double)dend_w[o2*64+o];
            s0 += ew*m0; s1 += ew*m1; s2 += ew*m2;
        }
        W[ODE0+i*32+o2]=s0; W[ODE1+i*32+o2]=s1; W[ODE2+i*32+o2]=s2;
    }
    for (int o2=tid; o2<32; o2+=nthr){
        double s = (double)dend_b[o2];
        for (int o=0;o<64;o++) s += (double)dend_w[o2*64+o]*((double)dg1_b[o]+(double)dg2_b[o]);
        W[ODEB+o2] = s;
        // fused relu-out: wc[o2] = sum_o3 w_end[o3]*dout_w[o3][o2]
        double wc = 0.0;
        for (int o3=0;o3<16;o3++) wc += (double)w_end[o3]*(double)dout_w[o3*32+o2];
        W[OWC+o2] = wc;
    }
    if (tid==0){
        double bc = (double)b_end[0];
        for (int o3=0;o3<16;o3++) bc += (double)w_end[o3]*(double)dout_b[o3];
        W[OBC] = bc;
    }
}

__global__ void k_emb(const int* __restrict__ idxp,
                      const float* __restrict__ emb1, const float* __restrict__ emb2,
                      const float* __restrict__ l1w, const float* __restrict__ l1b,
                      const float* __restrict__ l2w, const float* __restrict__ l2b,
                      double* __restrict__ n1, double* __restrict__ n2)
{
    int id = blockIdx.x*blockDim.x + threadIdx.x;   // 65536
    int i = id>>6, d = id&63;
    int ii = idxp[i];
    double a1 = (double)l1b[d], a2 = (double)l2b[d];
    for (int k=0;k<64;k++){
        a1 += (double)emb1[ii*64+k]*(double)l1w[d*64+k];
        a2 += (double)emb2[ii*64+k]*(double)l2w[d*64+k];
    }
    n1[id] = tanh(3.0*a1);
    n2[id] = tanh(3.0*a2);
}

__global__ __launch_bounds__(64) void k_topk(
    const double* __restrict__ n1, const double* __restrict__ n2,
    int* __restrict__ topc, double* __restrict__ topv,
    double* __restrict__ rs1, double* __restrict__ colsum)
{
    __shared__ double arow[NN];
    __shared__ double sn1[64], sn2[64];
    int i = blockIdx.x, lane = threadIdx.x;
    sn1[lane] = n1[i*64+lane];
    sn2[lane] = n2[i*64+lane];
    __syncthreads();
    for (int jb=0;jb<16;jb++){
        int j = jb*64 + lane;
        const double* p2 = n2 + j*64;
        const double* p1 = n1 + j*64;
        double d1v=0.0, d2v=0.0;
        for (int d=0;d<64;d++){ d1v += sn1[d]*p2[d]; d2v += sn2[d]*p1[d]; }
        double a = tanh(3.0*(d1v - d2v));
        arow[j] = a>0.0 ? a : 0.0;
    }
    __syncthreads();
    double rsum = 0.0;
    for (int r=0;r<TOPK;r++){
        double bv = -2.0; int bj = 1<<30;
        for (int jb=0;jb<16;jb++){
            int j = jb*64+lane;
            double v = arow[j];
            if (v>bv || (v==bv && j<bj)){ bv=v; bj=j; }
        }
        for (int off=32; off>=1; off>>=1){
            double ov = __shfl_xor(bv, off, 64);
            int    oj = __shfl_xor(bj, off, 64);
            if (ov>bv || (ov==bv && oj<bj)){ bv=ov; bj=oj; }
        }
        if (lane == (bj & 63)) arow[bj] = -2.0;
        if (lane == 0){
            topc[i*TOPK+r] = bj;
            topv[i*TOPK+r] = bv;
            if (bv > 0.0) atomicAdd(&colsum[bj], bv);
        }
        rsum += (bv > 0.0 ? bv : 0.0);
        __syncthreads();
    }
    if (lane == 0) rs1[i] = 1.0 + rsum;
}

__global__ void k_csc(const int* __restrict__ topc, const double* __restrict__ topv,
                      const double* __restrict__ rs1,
                      int* __restrict__ ccount, int* __restrict__ cidx, double* __restrict__ cw)
{
    int w = blockIdx.x*blockDim.x + threadIdx.x;
    if (w >= NN) return;
    double rv = rs1[w];
    for (int r=0;r<TOPK;r++){
        double v = topv[w*TOPK+r];
        if (v > 0.0){
            int col = topc[w*TOPK+r];
            int pos = atomicAdd(&ccount[col], 1);
            cidx[(long)col*NN+pos] = w;
            cw  [(long)col*NN+pos] = v / rv;
        }
    }
}

__global__ void k_post1(const double* __restrict__ colsum, const double* __restrict__ rs1,
                        double* __restrict__ rs2, double* __restrict__ d1, double* __restrict__ d2)
{
    int v = blockIdx.x*blockDim.x + threadIdx.x;
    if (v >= NN) return;
    double r2 = 1.0 + colsum[v];
    rs2[v] = r2;
    d2[v] = 1.0/r2;
    d1[v] = 1.0/rs1[v];
}

__global__ void k_post2(const int* __restrict__ topc, const double* __restrict__ topv,
                        const double* __restrict__ rs2, double* __restrict__ ew2)
{
    int e = blockIdx.x*blockDim.x + threadIdx.x;
    if (e >= NN*TOPK) return;
    double v = topv[e];
    ew2[e] = (v > 0.0) ? v / rs2[topc[e]] : 0.0;
}

// x[B,T,N] fp32 -> xT[B,N,T] fp32
__global__ __launch_bounds__(256) void k_xT(const float* __restrict__ x, float* __restrict__ xT)
{
    __shared__ float tile[32][33];
    int b = blockIdx.z, t0 = blockIdx.x*32, n0 = blockIdx.y*32;
    int tx = threadIdx.x, ty = threadIdx.y;
    const float* xb = x + (long)b*NTP;
    for (int r=0;r<4;r++){
        int tl = ty + 8*r;
        tile[tl][tx] = xb[(long)(t0+tl)*NN + n0 + tx];
    }
    __syncthreads();
    float* ob = xT + (long)b*NTP;
    for (int r=0;r<4;r++){
        int nl = ty + 8*r;
        ob[(long)(n0+nl)*TTL + t0 + tx] = tile[tx][nl];
    }
}

// ============ pipeline kernels ============

// encoder: gate (collapsed taps) fused into graph staging; t-tile=4, stride-6 LDS, double2 gather
__global__ __launch_bounds__(256) void k_enc_gg(const float* __restrict__ xT,
    double* __restrict__ eg, double* __restrict__ es1, double* __restrict__ es2,
    const double* __restrict__ Wt,
    const int* __restrict__ ccount, const int* __restrict__ cidx, const double* __restrict__ cw,
    const int* __restrict__ topc, const double* __restrict__ ew2,
    const double* __restrict__ d1, const double* __restrict__ d2,
    long S, int b0)
{
    __shared__ double ldsg[NN*6];   // 48 KB, stride 6 (pad 2)
    int tid = threadIdx.x, c = blockIdx.y, cb = blockIdx.z, t0 = blockIdx.x*4;
    double ft[3], fc[3], gt[3], gcc[3];
    #pragma unroll
    for (int k=0;k<3;k++){
        ft[k]=Wt[OEGTF_T+c*3+k]; fc[k]=Wt[OEGTF_C+c*3+k];
        gt[k]=Wt[OEGTG_T+c*3+k]; gcc[k]=Wt[OEGTG_C+c*3+k];
    }
    double fb = Wt[OEGTF_B+c], gb = Wt[OEGTG_B+c];
    const float* xb = xT + (long)(b0+cb)*NTP;
    long base = (long)c*S + (long)cb*NTP;
    for (int k=0;k<16;k++){
        int idx = k*256 + tid;
        int v = idx>>2, tl = idx&3, t = t0+tl;
        const float* xp = xb + (long)v*TTL + t;
        double xc = (double)xp[0];
        double atf = fb + ft[1]*xc + fc[1];
        double atg = gb + gt[1]*xc + gcc[1];
        if (t>0){ double xl = (double)xp[-1]; atf += ft[0]*xl + fc[0]; atg += gt[0]*xl + gcc[0]; }
        if (t<TTL-1){ double xr = (double)xp[1]; atf += ft[2]*xr + fc[2]; atg += gt[2]*xr + gcc[2]; }
        double gv = tanh(atf)/(1.0+exp(-atg));
        ldsg[v*6+tl] = gv;
        eg[base + (long)v*TTL + t] = gv;
    }
    __syncthreads();
    int wi = tid>>1, tl2 = tid&1;
    for (int wb=0;wb<8;wb++){
        int w = wb*128 + wi;
        double2 gc2 = *(const double2*)&ldsg[w*6 + 2*tl2];
        long p = base + (long)w*TTL + t0 + 2*tl2;
        double dv = d1[w];
        double a1x = gc2.x*dv, a1y = gc2.y*dv;
        int cnt = ccount[w];
        const int* ci = cidx + (long)w*NN;
        const double* cv = cw + (long)w*NN;
        for (int e=0;e<cnt;e++){
            double wt_ = cv[e];
            double2 s = *(const double2*)&ldsg[ci[e]*6 + 2*tl2];
            a1x += wt_*s.x; a1y += wt_*s.y;
        }
        double2 r1; r1.x=a1x; r1.y=a1y;
        *(double2*)&es1[p] = r1;
        double d2v = d2[w];
        double a2x = gc2.x*d2v, a2y = gc2.y*d2v;
        const int* tc = topc + w*TOPK;
        const double* e2 = ew2 + w*TOPK;
        for (int r=0;r<TOPK;r++){
            double wv = e2[r];
            if (wv != 0.0){
                double2 s = *(const double2*)&ldsg[tc[r]*6 + 2*tl2];
                a2x += wv*s.x; a2y += wv*s.y;
            }
        }
        double2 r2v; r2v.x=a2x; r2v.y=a2y;
        *(double2*)&es2[p] = r2v;
    }
}

// encoder tail: fused (mix.end) -> relu -> out64, all in registers
__global__ __launch_bounds__(256) void k_enc_tail(const double* __restrict__ eg,
    const double* __restrict__ es1, const double* __restrict__ es2,
    double* __restrict__ A, const double* __restrict__ Wt, long S)
{
    long p = (long)blockIdx.x*256 + threadIdx.x;
    double e[32];
    #pragma unroll
    for (int o2=0;o2<32;o2++) e[o2] = Wt[OEEB+o2];
    for (int i=0;i<16;i++){
        double a = eg[(long)i*S+p], b = es1[(long)i*S+p], c = es2[(long)i*S+p];
        const double* w0 = Wt+OEE0+i*32;
        const double* w1 = Wt+OEE1+i*32;
        const double* w2 = Wt+OEE2+i*32;
        #pragma unroll
        for (int o2=0;o2<32;o2++) e[o2] += w0[o2]*a + w1[o2]*b + w2[o2]*c;
    }
    #pragma unroll
    for (int o2=0;o2<32;o2++) e[o2] = e[o2]>0.0 ? e[o2] : 0.0;
    for (int o=0;o<64;o++){
        double acc = Wt[OEOUT_B+o];
        #pragma unroll
        for (int o2=0;o2<32;o2++) acc += Wt[OEOUT_W+o*32+o2]*e[o2];
        A[(long)o*S+p] = acc;
    }
}

// decoder gated tconv: one v-strip (128 t) per block, x staged in 64KB LDS,
// 2 passes x (og 2) = 4 chunks of 16 outputs -> 32 double accumulators (no spill)
__global__ __launch_bounds__(256) void k_dec_gate(const double* __restrict__ A,
    double* __restrict__ g, const double* __restrict__ Wt, long S)
{
    __shared__ double xs[64*TTL];   // 64 KB
    int tid = threadIdx.x;
    long vb = blockIdx.x;           // v + cb*1024
    for (int k=0;k<32;k++){
        int idx = k*256 + tid;
        int ch = idx>>7, t = idx&127;
        xs[idx] = A[(long)ch*S + vb*TTL + t];
    }
    __syncthreads();
    int t = tid&127, og = tid>>7;
    for (int pass=0;pass<2;pass++){
        int oc = pass*2 + og;
        double af[16], ag[16];
        #pragma unroll
        for (int o=0;o<16;o++){ af[o]=Wt[ODTF_B+oc*16+o]; ag[o]=Wt[ODTG_B+oc*16+o]; }
        for (int i=0;i<64;i++){
            const double* xr = xs + i*TTL;
            double xc = xr[t];
            double xl = (t>0)     ? xr[t-1] : 0.0;
            double xrr= (t<TTL-1) ? xr[t+1] : 0.0;
            const double* wf = Wt + ODTF_W + (long)i*192 + oc*48;
            const double* wg = Wt + ODTG_W + (long)i*192 + oc*48;
            #pragma unroll
            for (int o=0;o<16;o++){
                af[o] += wf[o*3]*xl + wf[o*3+1]*xc + wf[o*3+2]*xrr;
                ag[o] += wg[o*3]*xl + wg[o*3+1]*xc + wg[o*3+2]*xrr;
            }
        }
        #pragma unroll
        for (int o=0;o<16;o++){
            g[(long)(oc*16+o)*S + vb*TTL + t] = tanh(af[o])/(1.0+exp(-ag[o]));
        }
    }
}

// decoder pointwise fused-mix conv: g(=B[0:64]) -> P1,P2 (C[0:64]) then P0 -> B[0:32] (in-place, write-last)
__global__ __launch_bounds__(256) void k_dec_conv(double* B, double* __restrict__ C,
    const double* __restrict__ Wt, long S)
{
    long p = (long)blockIdx.x*256 + threadIdx.x;
    const double* g = B;
    double a1[32], a2[32];
    #pragma unroll
    for (int o2=0;o2<32;o2++){ a1[o2]=0.0; a2[o2]=0.0; }
    for (int i=0;i<64;i++){
        double gv = g[(long)i*S+p];
        const double* e1 = Wt+ODE1+i*32;
        const double* e2 = Wt+ODE2+i*32;
        #pragma unroll
        for (int o2=0;o2<32;o2++){ a1[o2] += e1[o2]*gv; a2[o2] += e2[o2]*gv; }
    }
    #pragma unroll
    for (int o2=0;o2<32;o2++){
        C[(long)o2*S+p] = a1[o2];
        C[(long)(32+o2)*S+p] = a2[o2];
    }
    double a0[32];
    #pragma unroll
    for (int o2=0;o2<32;o2++) a0[o2] = Wt[ODEB+o2];
    for (int i=0;i<64;i++){
        double gv = g[(long)i*S+p];
        const double* e0 = Wt+ODE0+i*32;
        #pragma unroll
        for (int o2=0;o2<32;o2++) a0[o2] += e0[o2]*gv;
    }
    #pragma unroll
    for (int o2=0;o2<32;o2++) B[(long)o2*S+p] = a0[o2];
}

// decoder graph gather on 32 fused channels x 2 directions: C -> A
__global__ __launch_bounds__(256) void k_graph32(const double* __restrict__ P, double* __restrict__ Q,
    const int* __restrict__ ccount, const int* __restrict__ cidx, const double* __restrict__ cw,
    const int* __restrict__ topc, const double* __restrict__ ew2,
    const double* __restrict__ d1, const double* __restrict__ d2, long S)
{
    __shared__ double lds[NN*6];   // 48 KB
    int tid = threadIdx.x;
    int y = blockIdx.y;            // 0..63: dir = y>>5, ch = y&31
    int dir = y>>5;
    long base = (long)y*S + (long)blockIdx.z*NTP;
    int t0 = blockIdx.x*4;
    const double* src = P + base;
    for (int k=0;k<16;k++){
        int idx = k*256 + tid;
        int v = idx>>2, tl = idx&3;
        lds[v*6+tl] = src[(long)v*TTL + t0 + tl];
    }
    __syncthreads();
    int wi = tid>>1, tl2 = tid&1;
    for (int wb=0;wb<8;wb++){
        int w = wb*128 + wi;
        double2 gc2 = *(const double2*)&lds[w*6 + 2*tl2];
        long p = base + (long)w*TTL + t0 + 2*tl2;
        double ax, ay;
        if (dir == 0){
            double dv = d1[w];
            ax = gc2.x*dv; ay = gc2.y*dv;
            int cnt = ccount[w];
            const int* ci = cidx + (long)w*NN;
            const double* cv = cw + (long)w*NN;
            for (int e=0;e<cnt;e++){
                double wt_ = cv[e];
                double2 s = *(const double2*)&lds[ci[e]*6 + 2*tl2];
                ax += wt_*s.x; ay += wt_*s.y;
            }
        } else {
            double dv = d2[w];
            ax = gc2.x*dv; ay = gc2.y*dv;
            const int* tc = topc + w*TOPK;
            const double* e2 = ew2 + w*TOPK;
            for (int r=0;r<TOPK;r++){
                double wv = e2[r];
                if (wv != 0.0){
                    double2 s = *(const double2*)&lds[tc[r]*6 + 2*tl2];
                    ax += wv*s.x; ay += wv*s.y;
                }
            }
        }
        double2 rv; rv.x=ax; rv.y=ay;
        *(double2*)&Q[p] = rv;
    }
}

// decoder tail: e = P0 + Q1 + Q2 -> relu -> fused (dout.w_end) dot -> fp32 [B,T,N]
__global__ __launch_bounds__(256) void k_dec_tail(const double* __restrict__ P0,
    const double* __restrict__ Q, const double* __restrict__ Wt,
    float* __restrict__ out, long S, int b0)
{
    long p = (long)blockIdx.x*256 + threadIdx.x;
    double res = Wt[OBC];
    #pragma unroll 8
    for (int o2=0;o2<32;o2++){
        double e = P0[(long)o2*S+p] + Q[(long)o2*S+p] + Q[(long)(32+o2)*S+p];
        e = e>0.0 ? e : 0.0;
        res += Wt[OWC+o2]*e;
    }
    int cb = (int)(p >> 17);
    long r = p & (NTP-1);
    int v = (int)(r >> 7), t = (int)(r & (TTL-1));
    out[((long)(b0+cb)*TTL + t)*NN + v] = (float)res;
}

// ============ launch ============

extern "C" void kernel_launch(void* const* d_in, const int* in_sizes, int n_in,
                              void* d_out, int out_size, void* d_ws, size_t ws_size,
                              hipStream_t stream)
{
    const float* x      = (const float*)d_in[0];
    const int*   idx    = (const int*)  d_in[1];
    const float* emb1   = (const float*)d_in[2];
    const float* emb2   = (const float*)d_in[3];
    const float* lin1_w = (const float*)d_in[4];
    const float* lin1_b = (const float*)d_in[5];
    const float* lin2_w = (const float*)d_in[6];
    const float* lin2_b = (const float*)d_in[7];
    const float* w_start= (const float*)d_in[8];
    const float* b_start= (const float*)d_in[9];
    const float* etf_w  = (const float*)d_in[10];
    const float* etf_b  = (const float*)d_in[11];
    const float* etg_w  = (const float*)d_in[12];
    const float* etg_b  = (const float*)d_in[13];
    const float* eg1_w  = (const float*)d_in[14];
    const float* eg1_b  = (const float*)d_in[15];
    const float* eg2_w  = (const float*)d_in[16];
    const float* eg2_b  = (const float*)d_in[17];
    const float* eend_w = (const float*)d_in[18];
    const float* eend_b = (const float*)d_in[19];
    const float* eout_w = (const float*)d_in[20];
    const float* eout_b = (const float*)d_in[21];
    const float* dtf_w  = (const float*)d_in[22];
    const float* dtf_b  = (const float*)d_in[23];
    const float* dtg_w  = (const float*)d_in[24];
    const float* dtg_b  = (const float*)d_in[25];
    const float* dg1_w  = (const float*)d_in[26];
    const float* dg1_b  = (const float*)d_in[27];
    const float* dg2_w  = (const float*)d_in[28];
    const float* dg2_b  = (const float*)d_in[29];
    const float* dend_w = (const float*)d_in[30];
    const float* dend_b = (const float*)d_in[31];
    const float* dout_w = (const float*)d_in[32];
    const float* dout_b = (const float*)d_in[33];
    const float* w_end  = (const float*)d_in[34];
    const float* b_end  = (const float*)d_in[35];
    float* out = (float*)d_out;

    char* basep = (char*)d_ws;
    size_t cur = 0;
    auto alloc = [&](size_t bytes)->void* {
        void* p = basep + cur;
        cur = (cur + bytes + 511) & ~(size_t)511;
        return p;
    };
    double* W     = (double*)alloc(WTOT*sizeof(double));
    double* n1    = (double*)alloc(65536*sizeof(double));
    double* n2    = (double*)alloc(65536*sizeof(double));
    double* topv  = (double*)alloc((size_t)NN*TOPK*sizeof(double));
    int*    topc  = (int*)   alloc((size_t)NN*TOPK*sizeof(int));
    double* rs1   = (double*)alloc(NN*sizeof(double));
    double* rs2   = (double*)alloc(NN*sizeof(double));
    double* colsum= (double*)alloc(NN*sizeof(double));
    double* d1a   = (double*)alloc(NN*sizeof(double));
    double* d2a   = (double*)alloc(NN*sizeof(double));
    double* ew2   = (double*)alloc((size_t)NN*TOPK*sizeof(double));
    int*    ccount= (int*)   alloc(NN*sizeof(int));
    int*    cidx  = (int*)   alloc((size_t)NN*NN*sizeof(int));
    double* cw    = (double*)alloc((size_t)NN*NN*sizeof(double));
    float*  xT    = (float*) alloc((size_t)16*NTP*sizeof(float));

    // plane arena: A(64) + B(64) + C(64) channel planes of CB*NTP doubles
    size_t perb = (size_t)192 * NTP * sizeof(double);
    int CB = 1;
    for (int c = 16; c >= 1; c >>= 1){
        if (cur + perb*(size_t)c <= ws_size){ CB = c; break; }
    }
    long S = (long)CB * NTP;
    double* A = (double*)alloc((size_t)64*S*sizeof(double));
    double* B = (double*)alloc((size_t)64*S*sizeof(double));
    double* C = (double*)alloc((size_t)64*S*sizeof(double));

    (void)hipMemsetAsync(colsum, 0, NN*sizeof(double), stream);
    (void)hipMemsetAsync(ccount, 0, NN*sizeof(int), stream);

    k_prep_weights<<<32,256,0,stream>>>(
        w_start,b_start, etf_w,etf_b, etg_w,etg_b, eg1_w,eg1_b, eg2_w,eg2_b,
        eend_w,eend_b, eout_w,eout_b, dtf_w,dtf_b, dtg_w,dtg_b, dg1_w,dg1_b,
        dg2_w,dg2_b, dend_w,dend_b, dout_w,dout_b, w_end,b_end, W);
    k_emb<<<256,256,0,stream>>>(idx, emb1, emb2, lin1_w, lin1_b, lin2_w, lin2_b, n1, n2);
    k_topk<<<NN,64,0,stream>>>(n1, n2, topc, topv, rs1, colsum);
    k_csc<<<4,256,0,stream>>>(topc, topv, rs1, ccount, cidx, cw);
    k_post1<<<4,256,0,stream>>>(colsum, rs1, rs2, d1a, d2a);
    k_post2<<<(NN*TOPK+255)/256,256,0,stream>>>(topc, topv, rs2, ew2);
    k_xT<<<dim3(4,32,16),dim3(32,8),0,stream>>>(x, xT);

    int nch = 16 / CB;
    for (int ch=0; ch<nch; ch++){
        int b0 = ch*CB;
        // encoder: fused gate+graph -> eg(B[0:16]), es1(B[16:32]), es2(B[32:48])
        k_enc_gg<<<dim3(32,16,CB),256,0,stream>>>(xT, B, B+(long)16*S, B+(long)32*S, W,
            ccount,cidx,cw, topc,ew2, d1a,d2a, S, b0);
        // encoder tail -> A (64 planes)
        k_enc_tail<<<512*CB,256,0,stream>>>(B, B+(long)16*S, B+(long)32*S, A, W, S);
        // decoder gate: A -> g (B[0:64])
        k_dec_gate<<<1024*CB,256,0,stream>>>(A, B, W, S);
        // decoder fused-mix conv: g -> P1,P2 (C), P0 (B[0:32], in-place write-last)
        k_dec_conv<<<512*CB,256,0,stream>>>(B, C, W, S);
        // decoder graph gather: C(P1,P2) -> A(Q1,Q2), 32ch x 2 dirs
        k_graph32<<<dim3(32,64,CB),256,0,stream>>>(C, A,
            ccount,cidx,cw, topc,ew2, d1a,d2a, S);
        // decoder tail -> out
        k_dec_tail<<<512*CB,256,0,stream>>>(B, A, W, out, S, b0);
    }
    (void)in_sizes; (void)n_in; (void)out_size;
}